// Round 1
// baseline (4297.503 us; speedup 1.0000x reference)
//
#include <hip/hip_runtime.h>

#define NNODES 100000

// ---------------- degree / dinv ----------------

__global__ __launch_bounds__(256) void deg_kernel(const int* __restrict__ dst,
                                                  float* __restrict__ deg, int E) {
    int e = blockIdx.x * 256 + threadIdx.x;
    if (e < E) atomicAdd(&deg[dst[e]], 1.0f);
}

__global__ __launch_bounds__(256) void dinv_kernel(float* __restrict__ deg, int N) {
    int i = blockIdx.x * 256 + threadIdx.x;
    if (i < N) deg[i] = rsqrtf(deg[i] + 1.0f);  // +1 for self loop; deg>=1 always
}

// ---------------- GEMM: Y[i,:] = dinv[i] * (X[i,:] @ W), K=128 fixed ----------------
// 256 threads, 4x4 micro-tile per thread.
// OD=128: JG=32 col-groups, TR=8 thread-rows, ROWS=32, LDS = 64KB(W)+16.9KB(X)
// OD=64 : JG=16, TR=16, ROWS=64, LDS = 32KB(W)+33.8KB(X)

template <int OD>
__global__ __launch_bounds__(256) void gemm_scale(const float* __restrict__ X,
                                                  const float* __restrict__ W,
                                                  const float* __restrict__ dinv,
                                                  float* __restrict__ Y, int N) {
    constexpr int K = 128;
    constexpr int KP = K + 4;          // pad keeps 16B alignment, breaks bank aliasing
    constexpr int JG = OD / 4;
    constexpr int TR = 256 / JG;
    constexpr int ROWS = TR * 4;

    __shared__ float sW[K * OD];
    __shared__ float sX[ROWS * KP];

    const int tid = threadIdx.x;

    // stage W (contiguous float4, coalesced)
    for (int i = tid; i < K * OD / 4; i += 256)
        ((float4*)sW)[i] = ((const float4*)W)[i];

    const int jg = tid % JG;
    const int tr = tid / JG;
    const int r0 = tr * 4;
    const int base = blockIdx.x * ROWS;

    // stage X rows [base, base+ROWS): thread t loads float4 at (row=t/32, k4=(t%32)*4)
    const int k4 = (tid & 31) * 4;
    for (int rl = tid >> 5; rl < ROWS; rl += 8) {
        int row = base + rl;
        float4 v = make_float4(0.f, 0.f, 0.f, 0.f);
        if (row < N) v = *(const float4*)(X + (size_t)row * K + k4);
        *(float4*)(sX + rl * KP + k4) = v;
    }
    __syncthreads();

    float acc[4][4] = {{0.f}};
#pragma unroll 8
    for (int k = 0; k < K; ++k) {
        float4 w = *(const float4*)(sW + k * OD + jg * 4);
        float x0 = sX[(r0 + 0) * KP + k];
        float x1 = sX[(r0 + 1) * KP + k];
        float x2 = sX[(r0 + 2) * KP + k];
        float x3 = sX[(r0 + 3) * KP + k];
        acc[0][0] += x0 * w.x; acc[0][1] += x0 * w.y; acc[0][2] += x0 * w.z; acc[0][3] += x0 * w.w;
        acc[1][0] += x1 * w.x; acc[1][1] += x1 * w.y; acc[1][2] += x1 * w.z; acc[1][3] += x1 * w.w;
        acc[2][0] += x2 * w.x; acc[2][1] += x2 * w.y; acc[2][2] += x2 * w.z; acc[2][3] += x2 * w.w;
        acc[3][0] += x3 * w.x; acc[3][1] += x3 * w.y; acc[3][2] += x3 * w.z; acc[3][3] += x3 * w.w;
    }

#pragma unroll
    for (int i = 0; i < 4; ++i) {
        int row = base + r0 + i;
        if (row < N) {
            float s = dinv[row];
            float4 o = make_float4(acc[i][0] * s, acc[i][1] * s, acc[i][2] * s, acc[i][3] * s);
            *(float4*)(Y + (size_t)row * OD + jg * 4) = o;
        }
    }
}

// ---------------- edge scatter: agg[dst,:] += Y[src,:] ----------------

template <int OD>
__global__ __launch_bounds__(256) void scatter_kernel(const int* __restrict__ ei, int E,
                                                      const float* __restrict__ Y,
                                                      float* __restrict__ agg) {
    constexpr int C = OD / 4;  // float4 chunks per edge (power of 2)
    int gid = blockIdx.x * 256 + threadIdx.x;
    int e = gid / C;
    if (e >= E) return;
    int c = gid % C;
    int src = ei[e];
    int dst = ei[E + e];
    float4 v = *(const float4*)(Y + (size_t)src * OD + c * 4);
    float* p = agg + (size_t)dst * OD + c * 4;
    atomicAdd(p + 0, v.x);
    atomicAdd(p + 1, v.y);
    atomicAdd(p + 2, v.z);
    atomicAdd(p + 3, v.w);
}

// ---------------- finish: out[i,:] = dinv[i]*(agg[i,:] + Y[i,:] (self loop)) + b ----------------

template <int OD>
__global__ __launch_bounds__(256) void finish_kernel(const float* __restrict__ agg,
                                                     const float* __restrict__ Y,
                                                     const float* __restrict__ dinv,
                                                     const float* __restrict__ bias,
                                                     float* __restrict__ out, int N) {
    constexpr int C = OD / 4;
    int gid = blockIdx.x * 256 + threadIdx.x;
    int i = gid / C;
    if (i >= N) return;
    int c = (gid % C) * 4;
    float s = dinv[i];
    float4 a = *(const float4*)(agg + (size_t)i * OD + c);
    float4 y = *(const float4*)(Y + (size_t)i * OD + c);
    float4 b = *(const float4*)(bias + c);
    float4 o;
    o.x = s * (a.x + y.x) + b.x;
    o.y = s * (a.y + y.y) + b.y;
    o.z = s * (a.z + y.z) + b.z;
    o.w = s * (a.w + y.w) + b.w;
    *(float4*)(out + (size_t)i * OD + c) = o;
}

// ---------------- launch ----------------

extern "C" void kernel_launch(void* const* d_in, const int* in_sizes, int n_in,
                              void* d_out, int out_size, void* d_ws, size_t ws_size,
                              hipStream_t stream) {
    const float* x  = (const float*)d_in[0];   // [N,128]
    const int*   ei = (const int*)d_in[1];     // [2,E] int32
    const float* W1 = (const float*)d_in[2];   // [128,128]
    const float* b1 = (const float*)d_in[3];   // [128]
    const float* W2 = (const float*)d_in[4];   // [128,64]
    const float* b2 = (const float*)d_in[5];   // [64]
    float* out = (float*)d_out;                // [N,64]

    const int N = NNODES;
    const int E = in_sizes[1] / 2;

    float* ws   = (float*)d_ws;
    float* dinv = ws;                           // N floats (deg -> dinv in place)
    float* buf1 = ws + N;                       // N*128: y1; later y2 [0,N*64) + agg2 [N*64,N*128)
    float* buf2 = ws + N + (size_t)N * 128;     // N*128: agg1 -> h (in place)

    // ws and d_out are poisoned 0xAA before every call: zero what we accumulate into.
    hipMemsetAsync(dinv, 0, (size_t)N * sizeof(float), stream);
    hipMemsetAsync(buf2, 0, (size_t)N * 128 * sizeof(float), stream);

    deg_kernel<<<(E + 255) / 256, 256, 0, stream>>>(ei + E, dinv, E);
    dinv_kernel<<<(N + 255) / 256, 256, 0, stream>>>(dinv, N);

    // layer 1
    gemm_scale<128><<<(N + 31) / 32, 256, 0, stream>>>(x, W1, dinv, buf1, N);
    {
        long long work = (long long)E * 32;
        scatter_kernel<128><<<(int)((work + 255) / 256), 256, 0, stream>>>(ei, E, buf1, buf2);
    }
    {
        long long work = (long long)N * 32;
        // h = dinv*(agg1 + y1) + b1, written over agg1 (elementwise, safe)
        finish_kernel<128><<<(int)((work + 255) / 256), 256, 0, stream>>>(buf2, buf1, dinv, b1, buf2, N);
    }

    // layer 2 (y1 dead; reuse buf1: y2 in first N*64, agg2 in second N*64)
    float* y2   = buf1;
    float* agg2 = buf1 + (size_t)N * 64;
    hipMemsetAsync(agg2, 0, (size_t)N * 64 * sizeof(float), stream);

    gemm_scale<64><<<(N + 63) / 64, 256, 0, stream>>>(buf2, W2, dinv, y2, N);
    {
        long long work = (long long)E * 16;
        scatter_kernel<64><<<(int)((work + 255) / 256), 256, 0, stream>>>(ei, E, y2, agg2);
    }
    {
        long long work = (long long)N * 16;
        finish_kernel<64><<<(int)((work + 255) / 256), 256, 0, stream>>>(agg2, y2, dinv, b2, out, N);
    }
}

// Round 2
// 629.937 us; speedup vs baseline: 6.8221x; 6.8221x over previous
//
#include <hip/hip_runtime.h>

#define NNODES 100000

// ================= CSR build: counting sort of edges by dst =================

__global__ __launch_bounds__(256) void count_kernel(const int* __restrict__ dst,
                                                    int* __restrict__ counts, int E) {
    int e = blockIdx.x * 256 + threadIdx.x;
    if (e < E) atomicAdd(&counts[dst[e]], 1);
}

// per-block exclusive scan of counts -> rowStart (pre-offset), block totals -> blockSums
__global__ __launch_bounds__(256) void scan_block_kernel(const int* __restrict__ counts,
                                                         int* __restrict__ rowStart,
                                                         int* __restrict__ blockSums, int N) {
    __shared__ int sh[256];
    int gid = blockIdx.x * 256 + threadIdx.x;
    int v = (gid < N) ? counts[gid] : 0;
    sh[threadIdx.x] = v;
    __syncthreads();
    for (int off = 1; off < 256; off <<= 1) {
        int t = (threadIdx.x >= off) ? sh[threadIdx.x - off] : 0;
        __syncthreads();
        sh[threadIdx.x] += t;
        __syncthreads();
    }
    if (gid < N) rowStart[gid] = sh[threadIdx.x] - v;  // exclusive within block
    if (threadIdx.x == 255) blockSums[blockIdx.x] = sh[255];
}

// exclusive scan of blockSums in place (NB <= 512)
__global__ __launch_bounds__(512) void scan_top_kernel(int* __restrict__ blockSums, int NB) {
    __shared__ int sh[512];
    int v = (threadIdx.x < NB) ? blockSums[threadIdx.x] : 0;
    sh[threadIdx.x] = v;
    __syncthreads();
    for (int off = 1; off < 512; off <<= 1) {
        int t = (threadIdx.x >= off) ? sh[threadIdx.x - off] : 0;
        __syncthreads();
        sh[threadIdx.x] += t;
        __syncthreads();
    }
    if (threadIdx.x < NB) blockSums[threadIdx.x] = sh[threadIdx.x] - v;
}

// rowStart += block offset; cursor = rowStart; dinv = rsqrt(count+1); rowStart[N] = E
__global__ __launch_bounds__(256) void apply_kernel(int* __restrict__ rowStart,
                                                    const int* __restrict__ blockSums,
                                                    const int* __restrict__ counts,
                                                    int* __restrict__ cursor,
                                                    float* __restrict__ dinv, int N, int E) {
    int gid = blockIdx.x * 256 + threadIdx.x;
    if (gid < N) {
        int rs = rowStart[gid] + blockSums[blockIdx.x];
        rowStart[gid] = rs;
        cursor[gid] = rs;
        dinv[gid] = rsqrtf((float)counts[gid] + 1.0f);  // +1 self loop
    }
    if (gid == 0) rowStart[N] = E;
}

__global__ __launch_bounds__(256) void permute_kernel(const int* __restrict__ ei, int E,
                                                      int* __restrict__ cursor,
                                                      int* __restrict__ sorted_src) {
    int e = blockIdx.x * 256 + threadIdx.x;
    if (e < E) {
        int dst = ei[E + e];
        int pos = atomicAdd(&cursor[dst], 1);
        sorted_src[pos] = ei[e];
    }
}

// ========== GEMM: Y[i,:] = dinv[i] * (X[i,:] @ W), K=128 fixed ==========

template <int OD>
__global__ __launch_bounds__(256) void gemm_scale(const float* __restrict__ X,
                                                  const float* __restrict__ W,
                                                  const float* __restrict__ dinv,
                                                  float* __restrict__ Y, int N) {
    constexpr int K = 128;
    constexpr int KP = K + 4;
    constexpr int JG = OD / 4;
    constexpr int TR = 256 / JG;
    constexpr int ROWS = TR * 4;

    __shared__ float sW[K * OD];
    __shared__ float sX[ROWS * KP];

    const int tid = threadIdx.x;

    for (int i = tid; i < K * OD / 4; i += 256)
        ((float4*)sW)[i] = ((const float4*)W)[i];

    const int jg = tid % JG;
    const int tr = tid / JG;
    const int r0 = tr * 4;
    const int base = blockIdx.x * ROWS;

    const int k4 = (tid & 31) * 4;
    for (int rl = tid >> 5; rl < ROWS; rl += 8) {
        int row = base + rl;
        float4 v = make_float4(0.f, 0.f, 0.f, 0.f);
        if (row < N) v = *(const float4*)(X + (size_t)row * K + k4);
        *(float4*)(sX + rl * KP + k4) = v;
    }
    __syncthreads();

    float acc[4][4] = {{0.f}};
#pragma unroll 8
    for (int k = 0; k < K; ++k) {
        float4 w = *(const float4*)(sW + k * OD + jg * 4);
        float x0 = sX[(r0 + 0) * KP + k];
        float x1 = sX[(r0 + 1) * KP + k];
        float x2 = sX[(r0 + 2) * KP + k];
        float x3 = sX[(r0 + 3) * KP + k];
        acc[0][0] += x0 * w.x; acc[0][1] += x0 * w.y; acc[0][2] += x0 * w.z; acc[0][3] += x0 * w.w;
        acc[1][0] += x1 * w.x; acc[1][1] += x1 * w.y; acc[1][2] += x1 * w.z; acc[1][3] += x1 * w.w;
        acc[2][0] += x2 * w.x; acc[2][1] += x2 * w.y; acc[2][2] += x2 * w.z; acc[2][3] += x2 * w.w;
        acc[3][0] += x3 * w.x; acc[3][1] += x3 * w.y; acc[3][2] += x3 * w.z; acc[3][3] += x3 * w.w;
    }

#pragma unroll
    for (int i = 0; i < 4; ++i) {
        int row = base + r0 + i;
        if (row < N) {
            float s = dinv[row];
            float4 o = make_float4(acc[i][0] * s, acc[i][1] * s, acc[i][2] * s, acc[i][3] * s);
            *(float4*)(Y + (size_t)row * OD + jg * 4) = o;
        }
    }
}

// ========== aggregate: out[i,:] = dinv[i]*(Y[i,:] + sum_{src->i} Y[src,:]) + b ==========
// TPN = OD/4 threads per node, float4 per thread. Register accumulation, no atomics.

template <int OD>
__global__ __launch_bounds__(256) void aggregate_kernel(const int* __restrict__ rowStart,
                                                        const int* __restrict__ sorted_src,
                                                        const float* __restrict__ Y,
                                                        const float* __restrict__ dinv,
                                                        const float* __restrict__ bias,
                                                        float* __restrict__ out, int N) {
    constexpr int TPN = OD / 4;       // 32 (OD=128) or 16 (OD=64)
    constexpr int NPB = 256 / TPN;    // 8 or 16 nodes per block
    int node = blockIdx.x * NPB + threadIdx.x / TPN;
    if (node >= N) return;
    int c4 = (threadIdx.x % TPN) * 4;

    float4 acc = *(const float4*)(Y + (size_t)node * OD + c4);  // self loop
    int s = rowStart[node];
    int e = rowStart[node + 1];
    for (int i = s; i < e; ++i) {
        int src = sorted_src[i];
        float4 v = *(const float4*)(Y + (size_t)src * OD + c4);
        acc.x += v.x; acc.y += v.y; acc.z += v.z; acc.w += v.w;
    }
    float di = dinv[node];
    float4 b = *(const float4*)(bias + c4);
    float4 o;
    o.x = di * acc.x + b.x;
    o.y = di * acc.y + b.y;
    o.z = di * acc.z + b.z;
    o.w = di * acc.w + b.w;
    *(float4*)(out + (size_t)node * OD + c4) = o;
}

// ================================ launch ================================

extern "C" void kernel_launch(void* const* d_in, const int* in_sizes, int n_in,
                              void* d_out, int out_size, void* d_ws, size_t ws_size,
                              hipStream_t stream) {
    const float* x  = (const float*)d_in[0];   // [N,128]
    const int*   ei = (const int*)d_in[1];     // [2,E] int32
    const float* W1 = (const float*)d_in[2];   // [128,128]
    const float* b1 = (const float*)d_in[3];   // [128]
    const float* W2 = (const float*)d_in[4];   // [128,64]
    const float* b2 = (const float*)d_in[5];   // [64]
    float* out = (float*)d_out;                // [N,64]

    const int N = NNODES;
    const int E = in_sizes[1] / 2;
    const int NB = (N + 255) / 256;            // scan blocks (391)

    // workspace layout
    float* ws   = (float*)d_ws;
    float* dinv = ws;                              // N
    float* y    = ws + N;                          // N*128 (y1, then y2 in first N*64)
    float* h    = y + (size_t)N * 128;             // N*128
    int* ip        = (int*)(h + (size_t)N * 128);
    int* counts    = ip;                           // N
    int* rowStart  = ip + N;                       // N+1
    int* cursor    = rowStart + N + 1;             // N
    int* blockSums = cursor + N;                   // 512
    int* sorted_src= blockSums + 512;              // E

    // ---- CSR build (shared by both layers) ----
    hipMemsetAsync(counts, 0, (size_t)N * sizeof(int), stream);
    count_kernel<<<(E + 255) / 256, 256, 0, stream>>>(ei + E, counts, E);
    scan_block_kernel<<<NB, 256, 0, stream>>>(counts, rowStart, blockSums, N);
    scan_top_kernel<<<1, 512, 0, stream>>>(blockSums, NB);
    apply_kernel<<<NB, 256, 0, stream>>>(rowStart, blockSums, counts, cursor, dinv, N, E);
    permute_kernel<<<(E + 255) / 256, 256, 0, stream>>>(ei, E, cursor, sorted_src);

    // ---- layer 1 ----
    gemm_scale<128><<<(N + 31) / 32, 256, 0, stream>>>(x, W1, dinv, y, N);
    aggregate_kernel<128><<<(N + 7) / 8, 256, 0, stream>>>(rowStart, sorted_src, y, dinv, b1, h, N);

    // ---- layer 2 (y buffer reused for y2) ----
    gemm_scale<64><<<(N + 63) / 64, 256, 0, stream>>>(h, W2, dinv, y, N);
    aggregate_kernel<64><<<(N + 15) / 16, 256, 0, stream>>>(rowStart, sorted_src, y, dinv, b2, out, N);
}

// Round 3
// 441.074 us; speedup vs baseline: 9.7433x; 1.4282x over previous
//
#include <hip/hip_runtime.h>

#define NNODES 100000

// ================= linked-list build: chains of in-edges per dst =================
// nx[e] = (next_edge_in_chain, src_node). head[dst] = most recent edge id, -1 = end.

__global__ __launch_bounds__(256) void build_chains(const int* __restrict__ ei, int E,
                                                    int* __restrict__ head,
                                                    int2* __restrict__ nx) {
    int e = blockIdx.x * 256 + threadIdx.x;
    if (e >= E) return;
    int src = ei[e];
    int dst = ei[E + e];
    int old = atomicExch(&head[dst], e);   // random atomic on 400 KB table
    nx[e] = make_int2(old, src);           // coalesced 8B write
}

// deg walk -> dinv = rsqrt(indeg + 1)
__global__ __launch_bounds__(256) void deg_dinv_kernel(const int* __restrict__ head,
                                                       const int2* __restrict__ nx,
                                                       float* __restrict__ dinv, int N) {
    int i = blockIdx.x * 256 + threadIdx.x;
    if (i >= N) return;
    int c = 0;
    int cur = head[i];
    while (cur >= 0) { ++c; cur = nx[cur].x; }
    dinv[i] = rsqrtf((float)c + 1.0f);
}

// s = S*1 : s_i = dinv_i * (dinv_i + sum_{src->i} dinv_src)
__global__ __launch_bounds__(256) void s_kernel(const int* __restrict__ head,
                                                const int2* __restrict__ nx,
                                                const float* __restrict__ dinv,
                                                float* __restrict__ s, int N) {
    int i = blockIdx.x * 256 + threadIdx.x;
    if (i >= N) return;
    float di = dinv[i];
    float sum = di;
    int cur = head[i];
    while (cur >= 0) {
        int2 t = nx[cur];
        sum += dinv[t.y];
        cur = t.x;
    }
    s[i] = di * sum;
}

// ================= tiny GEMMs: W12 = W1 @ W2 (128x64), bW2 = b1 @ W2 =================

__global__ __launch_bounds__(256) void w12_kernel(const float* __restrict__ W1,
                                                  const float* __restrict__ b1,
                                                  const float* __restrict__ W2,
                                                  float* __restrict__ W12,
                                                  float* __restrict__ bW2) {
    int j = threadIdx.x % 64;
    int r = threadIdx.x / 64;  // 0..3
    if (blockIdx.x < 32) {
        int i = blockIdx.x * 4 + r;
        float acc = 0.f;
        for (int k = 0; k < 128; ++k) acc += W1[i * 128 + k] * W2[k * 64 + j];
        W12[i * 64 + j] = acc;
    } else if (r == 0) {
        float acc = 0.f;
        for (int k = 0; k < 128; ++k) acc += b1[k] * W2[k * 64 + j];
        bW2[j] = acc;
    }
}

// ========== GEMM: Y[i,:] = dinv[i] * (X[i,:] @ W), K=128, OD=64 ==========

template <int OD>
__global__ __launch_bounds__(256) void gemm_scale(const float* __restrict__ X,
                                                  const float* __restrict__ W,
                                                  const float* __restrict__ dinv,
                                                  float* __restrict__ Y, int N) {
    constexpr int K = 128;
    constexpr int KP = K + 4;
    constexpr int JG = OD / 4;
    constexpr int TR = 256 / JG;
    constexpr int ROWS = TR * 4;

    __shared__ float sW[K * OD];
    __shared__ float sX[ROWS * KP];

    const int tid = threadIdx.x;

    for (int i = tid; i < K * OD / 4; i += 256)
        ((float4*)sW)[i] = ((const float4*)W)[i];

    const int jg = tid % JG;
    const int tr = tid / JG;
    const int r0 = tr * 4;
    const int base = blockIdx.x * ROWS;

    const int k4 = (tid & 31) * 4;
    for (int rl = tid >> 5; rl < ROWS; rl += 8) {
        int row = base + rl;
        float4 v = make_float4(0.f, 0.f, 0.f, 0.f);
        if (row < N) v = *(const float4*)(X + (size_t)row * K + k4);
        *(float4*)(sX + rl * KP + k4) = v;
    }
    __syncthreads();

    float acc[4][4] = {{0.f}};
#pragma unroll 8
    for (int k = 0; k < K; ++k) {
        float4 w = *(const float4*)(sW + k * OD + jg * 4);
        float x0 = sX[(r0 + 0) * KP + k];
        float x1 = sX[(r0 + 1) * KP + k];
        float x2 = sX[(r0 + 2) * KP + k];
        float x3 = sX[(r0 + 3) * KP + k];
        acc[0][0] += x0 * w.x; acc[0][1] += x0 * w.y; acc[0][2] += x0 * w.z; acc[0][3] += x0 * w.w;
        acc[1][0] += x1 * w.x; acc[1][1] += x1 * w.y; acc[1][2] += x1 * w.z; acc[1][3] += x1 * w.w;
        acc[2][0] += x2 * w.x; acc[2][1] += x2 * w.y; acc[2][2] += x2 * w.z; acc[2][3] += x2 * w.w;
        acc[3][0] += x3 * w.x; acc[3][1] += x3 * w.y; acc[3][2] += x3 * w.z; acc[3][3] += x3 * w.w;
    }

#pragma unroll
    for (int i = 0; i < 4; ++i) {
        int row = base + r0 + i;
        if (row < N) {
            float sc = dinv[row];
            float4 o = make_float4(acc[i][0] * sc, acc[i][1] * sc, acc[i][2] * sc, acc[i][3] * sc);
            *(float4*)(Y + (size_t)row * OD + jg * 4) = o;
        }
    }
}

// ========== aggregate over chains, OD=64, 16 threads/node ==========
// FINAL=false: z_i = dinv_i^2 * (Y_i + sum_src Y_src)          (ready for next S application)
// FINAL=true : out_i = dinv_i * (Y_i + sum_src Y_src) + s_i*bW2 + b2

template <bool FINAL>
__global__ __launch_bounds__(256) void aggregate_chain(const int* __restrict__ head,
                                                       const int2* __restrict__ nx,
                                                       const float* __restrict__ Y,
                                                       const float* __restrict__ dinv,
                                                       const float* __restrict__ s,
                                                       const float* __restrict__ bW2,
                                                       const float* __restrict__ b2,
                                                       float* __restrict__ out, int N) {
    int node = blockIdx.x * 16 + (threadIdx.x >> 4);
    if (node >= N) return;
    int c4 = (threadIdx.x & 15) * 4;

    float4 acc = *(const float4*)(Y + (size_t)node * 64 + c4);  // self loop
    int cur = head[node];
    while (cur >= 0) {
        int2 t = nx[cur];   // one 8B load: (next, src); same addr across the 16 lanes -> broadcast
        float4 v = *(const float4*)(Y + (size_t)t.y * 64 + c4);
        acc.x += v.x; acc.y += v.y; acc.z += v.z; acc.w += v.w;
        cur = t.x;
    }
    float di = dinv[node];
    float4 o;
    if (FINAL) {
        float si = s[node];
        float4 bb = *(const float4*)(bW2 + c4);
        float4 b = *(const float4*)(b2 + c4);
        o.x = di * acc.x + si * bb.x + b.x;
        o.y = di * acc.y + si * bb.y + b.y;
        o.z = di * acc.z + si * bb.z + b.z;
        o.w = di * acc.w + si * bb.w + b.w;
    } else {
        float d2 = di * di;
        o.x = d2 * acc.x; o.y = d2 * acc.y; o.z = d2 * acc.z; o.w = d2 * acc.w;
    }
    *(float4*)(out + (size_t)node * 64 + c4) = o;
}

// ================================ launch ================================

extern "C" void kernel_launch(void* const* d_in, const int* in_sizes, int n_in,
                              void* d_out, int out_size, void* d_ws, size_t ws_size,
                              hipStream_t stream) {
    const float* x  = (const float*)d_in[0];   // [N,128]
    const int*   ei = (const int*)d_in[1];     // [2,E] int32
    const float* W1 = (const float*)d_in[2];   // [128,128]
    const float* b1 = (const float*)d_in[3];   // [128]
    const float* W2 = (const float*)d_in[4];   // [128,64]
    const float* b2 = (const float*)d_in[5];   // [64]
    float* out = (float*)d_out;                // [N,64]

    const int N = NNODES;
    const int E = in_sizes[1] / 2;

    // workspace layout
    float* ws   = (float*)d_ws;
    float* dinv = ws;                          // N
    float* s    = dinv + N;                    // N
    float* y    = s + N;                       // N*64
    float* z    = y + (size_t)N * 64;          // N*64
    float* W12  = z + (size_t)N * 64;          // 128*64
    float* bW2  = W12 + 128 * 64;              // 64
    int*  head  = (int*)(bW2 + 64);            // N
    int2* nx    = (int2*)(head + N + 2);       // E int2 (8B aligned: offset even ints)

    // ---- graph structure (shared by both S applications) ----
    hipMemsetAsync(head, 0xFF, (size_t)N * sizeof(int), stream);  // head = -1
    build_chains<<<(E + 255) / 256, 256, 0, stream>>>(ei, E, head, nx);
    w12_kernel<<<33, 256, 0, stream>>>(W1, b1, W2, W12, bW2);     // independent of chains
    deg_dinv_kernel<<<(N + 255) / 256, 256, 0, stream>>>(head, nx, dinv, N);
    s_kernel<<<(N + 255) / 256, 256, 0, stream>>>(head, nx, dinv, s, N);

    // ---- out = S^2 (X @ W12) + s (x) (b1@W2) + b2 ----
    gemm_scale<64><<<(N + 63) / 64, 256, 0, stream>>>(x, W12, dinv, y, N);
    aggregate_chain<false><<<(N + 15) / 16, 256, 0, stream>>>(head, nx, y, dinv, nullptr, nullptr, nullptr, z, N);
    aggregate_chain<true><<<(N + 15) / 16, 256, 0, stream>>>(head, nx, z, dinv, s, bW2, b2, out, N);
}